// Round 7
// baseline (37.637 us; speedup 1.0000x reference)
//
#include <hip/hip_runtime.h>
#include <hip/hip_bf16.h>

// MultiScaleRoIAlign for FPN, direct gather (NCHW f32):
//   - channel-pure XCD partition (XCD x owns channels [32x,32x+32) for ALL
//     rois -> zero cross-XCD line duplication; per-XCD footprint ~5.6 MB)
//   - level-major roi sweep via device-side counting sort (prelude kernel):
//     while an XCD processes level-l rois, its working set (l3:128KB,
//     l2:512KB, l1:2MB, l0:~3MB sparse) is L2-resident -> cross-roi window
//     overlap hits L2 instead of refetching HBM (R5 measured 202 MB miss
//     with unsorted per-roi scheduling; touched-line union is ~45 MB).
//   - nontemporal output stores (streaming, no reuse).
// Level: lvl = clip(floor(4 + log2(sqrt(area)/224 + 1e-8)), 2, 5) - 2
// ALIGNED=False, roi w/h >= 1, mask (s > -1 && s < H) else 0.

#define C_DIM 256
#define OUTB 7
#define NBINS 49
#define PER_ROI 12544        // 256*49
#define NROI 512
#define CPB 32               // channels per block (= per XCD)
#define OUTS_PB (CPB * NBINS)   // 1568 outputs per block
#define TPB 256
#define NXCD 8

// ---------------- prelude: stable counting sort of rois by level ----------
__global__ __launch_bounds__(NROI) void lvlsort_k(
    const float* __restrict__ boxes, int* __restrict__ perm) {
  __shared__ int lvl_of[NROI];
  __shared__ int base[4];
  const int t = threadIdx.x;  // == roi
  const float4 b = ((const float4*)boxes)[t];
  const float bw = fmaxf(b.z - b.x, 0.0f);
  const float bh = fmaxf(b.w - b.y, 0.0f);
  const float lv = floorf(4.0f + log2f(sqrtf(bw * bh) / 224.0f + 1e-8f));
  const int l = (int)(fminf(fmaxf(lv, 2.0f), 5.0f)) - 2;  // 0..3
  lvl_of[t] = l;
  __syncthreads();
  if (t < 4) {  // histogram
    int c = 0;
    for (int i = 0; i < NROI; i++) c += (lvl_of[i] == t);
    base[t] = c;
  }
  __syncthreads();
  if (t == 0) {  // exclusive prefix
    int s = 0;
    for (int k = 0; k < 4; k++) { int c = base[k]; base[k] = s; s += c; }
  }
  __syncthreads();
  int rank = 0;  // stable rank within level (deterministic)
  for (int i = 0; i < t; i++) rank += (lvl_of[i] == l);
  perm[base[l] + rank] = t;
}

// ---------------- main: direct gather, level-sorted roi sweep -------------
__global__ __launch_bounds__(TPB) void msroi_xcd_kernel(
    const float* __restrict__ f0, const float* __restrict__ f1,
    const float* __restrict__ f2, const float* __restrict__ f3,
    const float* __restrict__ boxes, const int* __restrict__ perm,
    float* __restrict__ out) {
  // 4096 blocks; blockIdx round-robins XCDs. XCD x = cgroup x; s = d>>3
  // sweeps level-sorted roi slots 0..511.
  const int d   = blockIdx.x;
  const int xcd = d & (NXCD - 1);
  const int s   = d >> 3;              // 0..511
  const int r   = perm[s];             // level-sorted roi
  const int cb  = xcd * CPB;           // channel base
  const int n   = r >> 8;              // 256 rois per image
  const int tid = threadIdx.x;

  const float4 box = ((const float4*)boxes)[r];

  // ---- level selection (exact reference arithmetic; block-uniform) ----
  const float bwp = fmaxf(box.z - box.x, 0.0f);
  const float bhp = fmaxf(box.w - box.y, 0.0f);
  const float lv = floorf(4.0f + log2f(sqrtf(bwp * bhp) / 224.0f + 1e-8f));
  const int lvl = (int)(fminf(fmaxf(lv, 2.0f), 5.0f)) - 2;  // 0..3

  const float* __restrict__ feat;
  switch (lvl) {
    case 0:  feat = f0; break;
    case 1:  feat = f1; break;
    case 2:  feat = f2; break;
    default: feat = f3; break;
  }
  const int sh = 8 - lvl;          // W = H = 1 << sh
  const int H = 1 << sh, W = H;
  const int hw_sh = 2 * sh;
  const float scale = 1.0f / (float)(4 << lvl);

  // ---- ROI geometry (block-uniform) ----
  const float x1 = box.x * scale, y1 = box.y * scale;
  const float x2 = box.z * scale, y2 = box.w * scale;
  const float roi_w = fmaxf(x2 - x1, 1.0f);
  const float roi_h = fmaxf(y2 - y1, 1.0f);
  const float bin_w = roi_w / (float)OUTB;
  const float bin_h = roi_h / (float)OUTB;

  float* __restrict__ obase = out + (size_t)r * PER_ROI + (size_t)cb * NBINS;
  const float* __restrict__ fbase =
      feat + (((size_t)(n * C_DIM + cb)) << hw_sh);

  for (int le = tid; le < OUTS_PB; le += TPB) {
    const int cl  = le / NBINS;          // 0..31 (magic mul, const divisor)
    const int bin = le - cl * NBINS;
    const int py  = bin / OUTB;
    const int px  = bin - py * OUTB;

    // Boundary-sensitive: no fma contraction (mask must match numpy).
    const float ysf = __fadd_rn(y1, __fmul_rn((float)py + 0.5f, bin_h));
    const float xsf = __fadd_rn(x1, __fmul_rn((float)px + 0.5f, bin_w));
    const bool vy = (ysf > -1.0f) && (ysf < (float)H);
    const bool vx = (xsf > -1.0f) && (xsf < (float)W);
    const float vm = (vy && vx) ? 1.0f : 0.0f;

    float y = fminf(fmaxf(ysf, 0.0f), (float)(H - 1));
    float x = fminf(fmaxf(xsf, 0.0f), (float)(W - 1));
    const int y0 = min((int)floorf(y), H - 2);
    const int x0 = min((int)floorf(x), W - 2);
    const float ly = y - (float)y0;
    const float lx = x - (float)x0;
    const float wy0 = 1.0f - ly, wx0 = 1.0f - lx;

    const float* __restrict__ p =
        fbase + ((size_t)cl << hw_sh) + ((size_t)y0 << sh) + (size_t)x0;
    const float2 v0 = *reinterpret_cast<const float2*>(p);
    const float2 v1 = *reinterpret_cast<const float2*>(p + W);

    const float val =
        vm * (wy0 * (wx0 * v0.x + lx * v0.y) + ly * (wx0 * v1.x + lx * v1.y));
    __builtin_nontemporal_store(val, obase + le);
  }
}

extern "C" void kernel_launch(void* const* d_in, const int* in_sizes, int n_in,
                              void* d_out, int out_size, void* d_ws, size_t ws_size,
                              hipStream_t stream) {
  const float* f0 = (const float*)d_in[0];
  const float* f1 = (const float*)d_in[1];
  const float* f2 = (const float*)d_in[2];
  const float* f3 = (const float*)d_in[3];
  const float* boxes = (const float*)d_in[4];
  float* out = (float*)d_out;
  int* perm = (int*)d_ws;  // 512 ints (ws is >= MBs)

  lvlsort_k<<<1, NROI, 0, stream>>>(boxes, perm);
  dim3 grid(NROI * NXCD);  // 4096
  msroi_xcd_kernel<<<grid, TPB, 0, stream>>>(f0, f1, f2, f3, boxes, perm, out);
}

// Round 8
// 33.459 us; speedup vs baseline: 1.1249x; 1.1249x over previous
//
#include <hip/hip_runtime.h>
#include <hip/hip_bf16.h>

// MultiScaleRoIAlign for FPN, direct gather (NCHW f32):
//   - channel-pure XCD partition: XCD x owns channels [32x,32x+32) for ALL
//     rois (4 cgroups of 8) -> zero cross-XCD line duplication.
//   - level-sorted roi sweep: O(1)-depth ballot counting-sort prelude (one
//     512-thread block, ~us) writes perm; main kernel sweeps rois level-major
//     so the ~64 concurrently-resident rois per XCD share one level's plane
//     set (lvl1: 4MB, lvl2: 1MB for 32ch x 2img) -> cross-roi window overlap
//     hits L2 instead of refetching HBM.
//   - nontemporal output stores (streaming, no reuse).
// Level: lvl = clip(floor(4 + log2(sqrt(area)/224 + 1e-8)), 2, 5) - 2
// ALIGNED=False, roi w/h >= 1, mask (s > -1 && s < H) else 0.

#define C_DIM 256
#define OUTB 7
#define NBINS 49
#define PER_ROI 12544        // 256*49
#define NROI 512
#define CPB 8                // channels per block
#define OUTS_PB (CPB * NBINS)   // 392
#define TPB 256
#define NXCD 8

// ---------------- prelude: ballot counting sort (stable, parallel) --------
__global__ __launch_bounds__(NROI) void lvlsort_k(
    const float* __restrict__ boxes, int* __restrict__ perm) {
  const int t = threadIdx.x;        // == roi 0..511
  const int wave = t >> 6, lane = t & 63;
  const float4 b = ((const float4*)boxes)[t];
  const float bw = fmaxf(b.z - b.x, 0.0f);
  const float bh = fmaxf(b.w - b.y, 0.0f);
  const float lv = floorf(4.0f + log2f(sqrtf(bw * bh) / 224.0f + 1e-8f));
  const int l = (int)(fminf(fmaxf(lv, 2.0f), 5.0f)) - 2;  // 0..3

  __shared__ int wcnt[4][8];
  __shared__ int wbase[4][8];
  unsigned long long m[4];
#pragma unroll
  for (int k = 0; k < 4; k++) {
    m[k] = __ballot(l == k);
    if (lane == 0) wcnt[k][wave] = __popcll(m[k]);
  }
  __syncthreads();
  if (t == 0) {  // 32-entry serial prefix (trivial)
    int s = 0;
#pragma unroll
    for (int k = 0; k < 4; k++)
#pragma unroll
      for (int w = 0; w < 8; w++) { wbase[k][w] = s; s += wcnt[k][w]; }
  }
  __syncthreads();
  const unsigned long long below = (lane == 0) ? 0ull : (~0ull >> (64 - lane));
  const int rank = __popcll(m[l] & below);
  perm[wbase[l][wave] + rank] = t;
}

// ---------------- main: direct gather, level-sorted roi sweep -------------
__global__ __launch_bounds__(TPB) void msroi_xcd_kernel(
    const float* __restrict__ f0, const float* __restrict__ f1,
    const float* __restrict__ f2, const float* __restrict__ f3,
    const float* __restrict__ boxes, const int* __restrict__ perm,
    float* __restrict__ out) {
  // 16384 blocks. blockIdx round-robins XCDs (d&7). XCD x, slot s = d>>3:
  // roi-slot = s>>2 (sorted sweep), cgroup = x*4 + (s&3), channels cgroup*8.
  const int d      = blockIdx.x;
  const int xcd    = d & (NXCD - 1);
  const int s      = d >> 3;            // 0..2047
  const int r      = perm[s >> 2];      // level-sorted roi
  const int cgroup = xcd * 4 + (s & 3); // 0..31
  const int cb     = cgroup * CPB;      // channel base
  const int n      = r >> 8;            // 256 rois per image
  const int tid    = threadIdx.x;

  const float4 box = ((const float4*)boxes)[r];

  // ---- level selection (exact reference arithmetic; block-uniform) ----
  const float bwp = fmaxf(box.z - box.x, 0.0f);
  const float bhp = fmaxf(box.w - box.y, 0.0f);
  const float lv = floorf(4.0f + log2f(sqrtf(bwp * bhp) / 224.0f + 1e-8f));
  const int lvl = (int)(fminf(fmaxf(lv, 2.0f), 5.0f)) - 2;  // 0..3

  const float* __restrict__ feat;
  switch (lvl) {
    case 0:  feat = f0; break;
    case 1:  feat = f1; break;
    case 2:  feat = f2; break;
    default: feat = f3; break;
  }
  const int sh = 8 - lvl;          // W = H = 1 << sh
  const int H = 1 << sh, W = H;
  const int hw_sh = 2 * sh;
  const float scale = 1.0f / (float)(4 << lvl);

  // ---- ROI geometry (block-uniform) ----
  const float x1 = box.x * scale, y1 = box.y * scale;
  const float x2 = box.z * scale, y2 = box.w * scale;
  const float roi_w = fmaxf(x2 - x1, 1.0f);
  const float roi_h = fmaxf(y2 - y1, 1.0f);
  const float bin_w = roi_w / (float)OUTB;
  const float bin_h = roi_h / (float)OUTB;

  float* __restrict__ obase = out + (size_t)r * PER_ROI + (size_t)cb * NBINS;

#pragma unroll
  for (int half = 0; half < 2; half++) {
    const int le = tid + half * TPB;
    if (le >= OUTS_PB) break;
    const int cl  = le / NBINS;          // magic mul (const divisor)
    const int bin = le - cl * NBINS;
    const int py  = bin / OUTB;
    const int px  = bin - py * OUTB;

    // Boundary-sensitive: no fma contraction (mask must match numpy).
    const float ysf = __fadd_rn(y1, __fmul_rn((float)py + 0.5f, bin_h));
    const float xsf = __fadd_rn(x1, __fmul_rn((float)px + 0.5f, bin_w));
    const bool vy = (ysf > -1.0f) && (ysf < (float)H);
    const bool vx = (xsf > -1.0f) && (xsf < (float)W);
    const float vm = (vy && vx) ? 1.0f : 0.0f;

    float y = fminf(fmaxf(ysf, 0.0f), (float)(H - 1));
    float x = fminf(fmaxf(xsf, 0.0f), (float)(W - 1));
    const int y0 = min((int)floorf(y), H - 2);
    const int x0 = min((int)floorf(x), W - 2);
    const float ly = y - (float)y0;
    const float lx = x - (float)x0;
    const float wy0 = 1.0f - ly, wx0 = 1.0f - lx;

    const float* __restrict__ p =
        feat + (((size_t)(n * C_DIM + cb + cl)) << hw_sh) +
        ((size_t)y0 << sh) + (size_t)x0;
    const float2 v0 = *reinterpret_cast<const float2*>(p);
    const float2 v1 = *reinterpret_cast<const float2*>(p + W);

    const float val =
        vm * (wy0 * (wx0 * v0.x + lx * v0.y) + ly * (wx0 * v1.x + lx * v1.y));
    __builtin_nontemporal_store(val, obase + le);
  }
}

extern "C" void kernel_launch(void* const* d_in, const int* in_sizes, int n_in,
                              void* d_out, int out_size, void* d_ws, size_t ws_size,
                              hipStream_t stream) {
  const float* f0 = (const float*)d_in[0];
  const float* f1 = (const float*)d_in[1];
  const float* f2 = (const float*)d_in[2];
  const float* f3 = (const float*)d_in[3];
  const float* boxes = (const float*)d_in[4];
  float* out = (float*)d_out;
  int* perm = (int*)d_ws;  // 512 ints

  lvlsort_k<<<1, NROI, 0, stream>>>(boxes, perm);
  dim3 grid(NROI * (C_DIM / CPB));  // 16384
  msroi_xcd_kernel<<<grid, TPB, 0, stream>>>(f0, f1, f2, f3, boxes, perm, out);
}

// Round 9
// 26.510 us; speedup vs baseline: 1.4198x; 1.2621x over previous
//
#include <hip/hip_runtime.h>
#include <hip/hip_bf16.h>

// MultiScaleRoIAlign for FPN, direct gather (NCHW f32), channel-partitioned
// XCD scheduling.  (R6 structure — best measured: 26.7 us.)
//   feats: stride {4,8,16,32} -> (2,256,256,256)/(2,256,128,128)/(2,256,64,64)/(2,256,32,32)
//   boxes: (2,256,4) xyxy, IMG=1024; out: (512,256,7,7) f32
// Level: lvl = clip(floor(4 + log2(sqrt(area)/224 + 1e-8)), 2, 5) - 2
// ALIGNED=False, roi w/h >= 1, mask (s > -1 && s < H) else 0.
//
// Scheduling: channels are DISJOINT data across blocks. XCD x owns channel
// groups [4x,4x+4) (8 ch each) and sweeps all 512 rois roi-major (image-major
// too, since r ascends): every feature-plane line is fetched by exactly ONE
// XCD's L2; live window set (~64 rois x 48KB) fits the 4 MB L2, so cross-roi
// window overlap hits L2 instead of refetching HBM. R5 measured 202 MB miss
// traffic with per-roi scheduling; this schedule cut time 43.2 -> 26.7 us.
// Level-sorted sweeps (R7/R8) were tried and are SLOWER (perm dependent-load
// prefix per block; reuse model overestimated) — do not re-add.
// Output stores nontemporal (streaming, no reuse; keeps L2 for windows).

#define C_DIM 256
#define OUTB 7
#define NBINS 49
#define PER_ROI 12544        // 256*49
#define NROI 512
#define CPB 8                // channels per block
#define OUTS_PB (CPB * NBINS)   // 392 outputs per block
#define TPB 256
#define NXCD 8

__global__ __launch_bounds__(TPB) void msroi_xcd_kernel(
    const float* __restrict__ f0, const float* __restrict__ f1,
    const float* __restrict__ f2, const float* __restrict__ f3,
    const float* __restrict__ boxes, float* __restrict__ out) {
  // 16384 blocks. blockIdx round-robins XCDs (d&7). XCD x gets slots s=d>>3:
  // roi = s>>2 (roi-major sweep), local cgroup = s&3, cgroup = x*4 + (s&3).
  const int d      = blockIdx.x;
  const int xcd    = d & (NXCD - 1);
  const int s      = d >> 3;            // 0..2047
  const int r      = s >> 2;            // 0..511
  const int cgroup = xcd * 4 + (s & 3); // 0..31
  const int cb     = cgroup * CPB;      // channel base
  const int n      = r >> 8;            // 256 rois per image
  const int tid    = threadIdx.x;

  const float4 box = ((const float4*)boxes)[r];

  // ---- level selection (exact reference arithmetic; block-uniform) ----
  float bwp = fmaxf(box.z - box.x, 0.0f);
  float bhp = fmaxf(box.w - box.y, 0.0f);
  float lv = floorf(4.0f + log2f(sqrtf(bwp * bhp) / 224.0f + 1e-8f));
  const int lvl = (int)(fminf(fmaxf(lv, 2.0f), 5.0f)) - 2;  // 0..3

  const float* __restrict__ feat;
  switch (lvl) {
    case 0:  feat = f0; break;
    case 1:  feat = f1; break;
    case 2:  feat = f2; break;
    default: feat = f3; break;
  }
  const int sh = 8 - lvl;          // W = H = 1 << sh
  const int H = 1 << sh, W = H;
  const int hw_sh = 2 * sh;
  const float scale = 1.0f / (float)(4 << lvl);

  // ---- ROI geometry (block-uniform part) ----
  const float x1 = box.x * scale, y1 = box.y * scale;
  const float x2 = box.z * scale, y2 = box.w * scale;
  const float roi_w = fmaxf(x2 - x1, 1.0f);
  const float roi_h = fmaxf(y2 - y1, 1.0f);
  const float bin_w = roi_w / (float)OUTB;
  const float bin_h = roi_h / (float)OUTB;

  float* __restrict__ obase = out + (size_t)r * PER_ROI + (size_t)cb * NBINS;

  // Each thread: outputs le = tid and le = tid + 256 (if < 392).
#pragma unroll
  for (int half = 0; half < 2; half++) {
    const int le = tid + half * TPB;
    if (le >= OUTS_PB) break;
    const int cl  = le / NBINS;          // 0..7 (magic mul, const divisor)
    const int bin = le - cl * NBINS;
    const int py  = bin / OUTB;
    const int px  = bin - py * OUTB;

    // Boundary-sensitive: no fma contraction (mask must match numpy).
    const float ysf = __fadd_rn(y1, __fmul_rn((float)py + 0.5f, bin_h));
    const float xsf = __fadd_rn(x1, __fmul_rn((float)px + 0.5f, bin_w));
    const bool vy = (ysf > -1.0f) && (ysf < (float)H);
    const bool vx = (xsf > -1.0f) && (xsf < (float)W);
    const float vm = (vy && vx) ? 1.0f : 0.0f;

    float y = fminf(fmaxf(ysf, 0.0f), (float)(H - 1));
    float x = fminf(fmaxf(xsf, 0.0f), (float)(W - 1));
    const int y0 = min((int)floorf(y), H - 2);
    const int x0 = min((int)floorf(x), W - 2);
    const float ly = y - (float)y0;
    const float lx = x - (float)x0;
    const float wy0 = 1.0f - ly, wx0 = 1.0f - lx;

    const float* __restrict__ p =
        feat + (((size_t)(n * C_DIM + cb + cl)) << hw_sh) +
        ((size_t)y0 << sh) + (size_t)x0;
    const float2 v0 = *reinterpret_cast<const float2*>(p);
    const float2 v1 = *reinterpret_cast<const float2*>(p + W);

    const float val =
        vm * (wy0 * (wx0 * v0.x + lx * v0.y) + ly * (wx0 * v1.x + lx * v1.y));
    // Streaming store: keep out of L2 so window lines stay resident.
    __builtin_nontemporal_store(val, obase + le);
  }
}

extern "C" void kernel_launch(void* const* d_in, const int* in_sizes, int n_in,
                              void* d_out, int out_size, void* d_ws, size_t ws_size,
                              hipStream_t stream) {
  const float* f0 = (const float*)d_in[0];
  const float* f1 = (const float*)d_in[1];
  const float* f2 = (const float*)d_in[2];
  const float* f3 = (const float*)d_in[3];
  const float* boxes = (const float*)d_in[4];
  float* out = (float*)d_out;

  dim3 grid(NROI * (C_DIM / CPB));  // 16384
  dim3 block(TPB);
  msroi_xcd_kernel<<<grid, block, 0, stream>>>(f0, f1, f2, f3, boxes, out);
}